// Round 9
// baseline (2260.867 us; speedup 1.0000x reference)
//
#include <hip/hip_runtime.h>
#include <stdint.h>

#define R_ 4096
#define L_ 32
#define C_ 512
#define H_ 4
#define DH_ 128

typedef __bf16 bf16x8 __attribute__((ext_vector_type(8)));
typedef float f32x4 __attribute__((ext_vector_type(4)));

// ---------- bf16 bit helpers (RNE) ----------
__device__ __forceinline__ float b2f(unsigned int u) {
    union { unsigned int i; float f; } x; x.i = u << 16; return x.f;
}
__device__ __forceinline__ unsigned short f2b(float f) {
    union { float f; unsigned int i; } x; x.f = f;
    unsigned int i = x.i;
    i += 0x7fffu + ((i >> 16) & 1u);
    return (unsigned short)(i >> 16);
}
__device__ __forceinline__ void unpack8(uint4 v, float* x) {
    x[0] = b2f(v.x & 0xffffu); x[1] = b2f(v.x >> 16);
    x[2] = b2f(v.y & 0xffffu); x[3] = b2f(v.y >> 16);
    x[4] = b2f(v.z & 0xffffu); x[5] = b2f(v.z >> 16);
    x[6] = b2f(v.w & 0xffffu); x[7] = b2f(v.w >> 16);
}
__device__ __forceinline__ uint4 pack8(const float* x) {
    uint4 v;
    v.x = (unsigned)f2b(x[0]) | ((unsigned)f2b(x[1]) << 16);
    v.y = (unsigned)f2b(x[2]) | ((unsigned)f2b(x[3]) << 16);
    v.z = (unsigned)f2b(x[4]) | ((unsigned)f2b(x[5]) << 16);
    v.w = (unsigned)f2b(x[6]) | ((unsigned)f2b(x[7]) << 16);
    return v;
}

// async global->LDS, 16B per lane; LDS dest = wave-uniform base + lane*16
__device__ __forceinline__ void gload_lds16(const unsigned short* g, unsigned short* l) {
    __builtin_amdgcn_global_load_lds(
        (const __attribute__((address_space(1))) void*)g,
        (__attribute__((address_space(3))) void*)l, 16, 0, 0);
}

// ---------- dtype detection: 1 = bf16, 0 = fp32 ----------
__global__ __launch_bounds__(256)
void detect_kernel(const unsigned short* __restrict__ gene, int* __restrict__ flag) {
    __shared__ int cnt;
    if (threadIdx.x == 0) cnt = 0;
    __syncthreads();
    int local = 0;
    for (int j = 0; j < 8; ++j) {
        int i = threadIdx.x * 8 + j;
        unsigned short u = gene[2 * i];
        int e = (u >> 7) & 0xFF;
        if (e >= 100 && e <= 140) ++local;
    }
    atomicAdd(&cnt, local);
    __syncthreads();
    if (threadIdx.x == 0) *flag = (cnt >= 1024) ? 1 : 0;
}

// ---------- convert (fp32|bf16) -> bf16 with source element offset ----------
__global__ __launch_bounds__(256)
void cvt_any_kernel(const void* __restrict__ in, unsigned short* __restrict__ out,
                    int n, const int* __restrict__ flag, int src_off) {
    int i0 = (blockIdx.x * 256 + threadIdx.x) * 8;
    if (i0 >= n) return;
    if (*flag) {
        *(uint4*)(out + i0) = *(const uint4*)((const unsigned short*)in + src_off + i0);
    } else {
        const float* f = (const float*)in + src_off;
        float4 a = *(const float4*)(f + i0);
        float4 b = *(const float4*)(f + i0 + 4);
        float x[8] = {a.x, a.y, a.z, a.w, b.x, b.y, b.z, b.w};
        *(uint4*)(out + i0) = pack8(x);
    }
}

// ---------- concat biases: bqkv0/1 [1536], bkv2 [1024] from cbq/cbk/cbv ----------
__global__ __launch_bounds__(256)
void bias_concat_kernel(const unsigned short* __restrict__ bq, const unsigned short* __restrict__ bk,
                        const unsigned short* __restrict__ bv,
                        unsigned short* __restrict__ bqkv0, unsigned short* __restrict__ bqkv1,
                        unsigned short* __restrict__ bkv2) {
    int t = threadIdx.x;
#pragma unroll
    for (int s = 0; s < 2; ++s) {
        int i = t + s * 256;
        bqkv0[i]        = bq[i];
        bqkv0[i + 512]  = bk[i];
        bqkv0[i + 1024] = bv[i];
        bqkv1[i]        = bq[i + 512];
        bqkv1[i + 512]  = bk[i + 512];
        bqkv1[i + 1024] = bv[i + 512];
        bkv2[i]         = bk[i + 1024];
        bkv2[i + 512]   = bv[i + 1024];
    }
}

// ---------- PMA query: qp[512] = Wq2 . seed + bq2 (seed is broadcast -> one row) ----------
__global__ __launch_bounds__(256)
void qp_kernel(const unsigned short* __restrict__ Wq2, const unsigned short* __restrict__ bq2,
               const unsigned short* __restrict__ seed, unsigned short* __restrict__ qp) {
    __shared__ float sv[512];
    int t = threadIdx.x;
    sv[t] = b2f(seed[t]); sv[t + 256] = b2f(seed[t + 256]);
    __syncthreads();
#pragma unroll
    for (int s = 0; s < 2; ++s) {
        int n = t + s * 256;
        const unsigned short* wrow = Wq2 + (size_t)n * 512;
        float acc = 0.f;
        for (int k8 = 0; k8 < 64; ++k8) {
            float x[8];
            unpack8(*(const uint4*)(wrow + k8 * 8), x);
#pragma unroll
            for (int e = 0; e < 8; ++e) acc += x[e] * sv[k8 * 8 + e];
        }
        qp[n] = f2b(acc + b2f(bq2[n]));
    }
}

// ---------- Wc = Wo3 @ Wv3 (decoder collapse: softmax over 1 key == identity) ----------
__global__ __launch_bounds__(256)
void wc_kernel(const unsigned short* __restrict__ Wo3, const unsigned short* __restrict__ Wv3,
               unsigned short* __restrict__ Wc) {
    const int i = blockIdx.x, t = threadIdx.x;
    __shared__ float wo[512];
    wo[t] = b2f(Wo3[(size_t)i * 512 + t]);
    wo[t + 256] = b2f(Wo3[(size_t)i * 512 + t + 256]);
    __syncthreads();
    float a0 = 0.f, a1 = 0.f;
    for (int d = 0; d < 512; ++d) {
        const unsigned short* row = Wv3 + (size_t)d * 512;
        float w = wo[d];
        a0 += w * b2f(row[t]);
        a1 += w * b2f(row[t + 256]);
    }
    Wc[(size_t)i * 512 + t]       = f2b(a0);
    Wc[(size_t)i * 512 + t + 256] = f2b(a1);
}

// ---------- bc = Wo3 @ bv3 + bo3 ----------
__global__ __launch_bounds__(256)
void bc_kernel(const unsigned short* __restrict__ Wo3, const unsigned short* __restrict__ bv3,
               const unsigned short* __restrict__ bo3, unsigned short* __restrict__ bc) {
    const int t = threadIdx.x;
    __shared__ float bvv[512];
    bvv[t] = b2f(bv3[t]); bvv[t + 256] = b2f(bv3[t + 256]);
    __syncthreads();
    const int i = blockIdx.x * 256 + t;
    const unsigned short* row = Wo3 + (size_t)i * 512;
    float acc = 0.f;
    for (int d8 = 0; d8 < 64; ++d8) {
        float x[8];
        unpack8(*(const uint4*)(row + d8 * 8), x);
#pragma unroll
        for (int e = 0; e < 8; ++e) acc += x[e] * bvv[d8 * 8 + e];
    }
    bc[i] = f2b(acc + b2f(bo3[i]));
}

// ---------- diagnostic ----------
__global__ __launch_bounds__(256)
void diag_kernel(unsigned short* __restrict__ out, int n, float val) {
    int i = blockIdx.x * 256 + threadIdx.x;
    if (i < n) out[i] = f2b(val);
}

// ---------- exclusive scan of lens -> off; meta[0]=total, meta[1]=totalPad(128) ----------
__global__ __launch_bounds__(256)
void scan_kernel(const int* __restrict__ lens, int* __restrict__ off,
                 int* __restrict__ meta, int Rc) {
    __shared__ int tsum[257];
    const int t = threadIdx.x;
    const int chunk = (Rc + 255) / 256;
    const int lo = t * chunk;
    const int hi = min(lo + chunk, Rc);
    int s = 0;
    for (int i = lo; i < hi; ++i) {
        int l = lens[i]; l = max(0, min(32, l));
        s += l;
    }
    tsum[t] = s;
    __syncthreads();
    if (t == 0) {
        int acc = 0;
        for (int i = 0; i < 256; ++i) { int v = tsum[i]; tsum[i] = acc; acc += v; }
        tsum[256] = acc;
        meta[0] = acc;
        meta[1] = (acc + 127) & ~127;
    }
    __syncthreads();
    int run = tsum[t];
    for (int i = lo; i < hi; ++i) {
        off[i] = run;
        int l = lens[i]; l = max(0, min(32, l));
        run += l;
    }
}

// ---------- gather genes -> compacted X rows [off[r]+j], j<len[r] ----------
__global__ __launch_bounds__(256)
void gather_kernel(const void* __restrict__ gene_v, const int* __restrict__ gidx,
                   const int* __restrict__ lens, const int* __restrict__ off,
                   unsigned short* __restrict__ X, const int* __restrict__ flag) {
    int tid = blockIdx.x * 256 + threadIdx.x;
    int m = tid >> 6;
    int ch = tid & 63;
    int r = m >> 5, j = m & 31;
    if (j >= lens[r]) return;
    size_t dst = (size_t)(off[r] + j) * C_ + ch * 8;
    size_t base = (size_t)gidx[m] * C_ + ch * 8;
    uint4 v;
    if (*flag) {
        v = *(const uint4*)((const unsigned short*)gene_v + base);
    } else {
        const float* f = (const float*)gene_v;
        float4 a = *(const float4*)(f + base);
        float4 b = *(const float4*)(f + base + 4);
        float x[8] = {a.x, a.y, a.z, a.w, b.x, b.y, b.z, b.w};
        v = pack8(x);
    }
    *(uint4*)(X + dst) = v;
}

// ---------- zero pad rows total..totalPad-1 (<=127 rows); grid 32 blocks ----------
__global__ __launch_bounds__(256)
void ztail_kernel(unsigned short* __restrict__ X, const int* __restrict__ meta) {
    int tid = blockIdx.x * 256 + threadIdx.x;
    int m = meta[0] + (tid >> 6);
    int ch = tid & 63;
    if (m < meta[1])
        *(uint4*)(X + (size_t)m * C_ + ch * 8) = make_uint4(0u, 0u, 0u, 0u);
}

// ---------- GEMM: Out[M, NT*256] = A @ W^T + bias, opt ReLU ----------
// R3-proven structure: 128x256 tile, BK=64 (8 K-iters), single-buffer LDS,
// XOR-swizzled (both-sides involution), global_load_lds 16B staging.
// (R4's explicit 2-phase dbuf regressed 15-20% -- do not re-add.)
// XCD co-residency decode: all NT n-tiles of one m-tile on the same XCD.
// launch_bounds(256,3): VGPR 100 << 170 budget; allows 3 blocks/CU (LDS 48KB x3).
template<int NT>
__global__ __launch_bounds__(256, 3)
void gemm_bt_kernel(const unsigned short* __restrict__ A, const unsigned short* __restrict__ W,
                    const unsigned short* __restrict__ bias, unsigned short* __restrict__ Out,
                    int relu, const int* __restrict__ meta, int MT) {
    const int b = blockIdx.x;
    const int xcd = b & 7;
    const int j = b >> 3;
    const int ml = j / NT;
    const int n = j - ml * NT;
    const int m = ml * 8 + xcd;
    if (m >= MT) return;
    const int m0 = m * 128, n0 = n * 256;
    if (meta && m0 >= meta[1]) return;   // block-uniform, before any barrier
    const int ldo = NT * 256;

    __shared__ unsigned short As[128 * 64];
    __shared__ unsigned short Bs[256 * 64];

    const int t = threadIdx.x;
    const int wave = t >> 6, lane = t & 63;
    const int quad = lane >> 4, lr = lane & 15;
    const int wr = wave >> 1, wc = wave & 1;

    // staging: lane covers row (l>>3), 16B chunk col8 = (l&7) ^ (l>>3)
    // (pre-swizzled global source, linear LDS dest)
    const int srow8 = lane >> 3;
    const int scol8 = (lane & 7) ^ srow8;
    const unsigned short* gaB = A + (size_t)(m0 + wave * 8 + srow8) * C_ + scol8 * 8;
    const unsigned short* gbB = W + (size_t)(n0 + wave * 8 + srow8) * C_ + scol8 * 8;
    unsigned short* lA = As + wave * 512;
    unsigned short* lB = Bs + wave * 512;

    f32x4 acc[4][8] = {};

    for (int k0 = 0; k0 < C_; k0 += 64) {
        __syncthreads();
#pragma unroll
        for (int jj = 0; jj < 4; ++jj)
            gload_lds16(gaB + (size_t)jj * 32 * C_ + k0, lA + jj * 2048);
#pragma unroll
        for (int jj = 0; jj < 8; ++jj)
            gload_lds16(gbB + (size_t)jj * 32 * C_ + k0, lB + jj * 2048);
        __syncthreads();

#pragma unroll
        for (int kk = 0; kk < 2; ++kk) {
            bf16x8 af[4], bfr[8];
#pragma unroll
            for (int i = 0; i < 4; ++i)
                af[i] = *(const bf16x8*)&As[(64 * wr + 16 * i + lr) * 64 +
                                            (((kk << 2) + quad) ^ (lr & 7)) * 8];
#pragma unroll
            for (int jj = 0; jj < 8; ++jj)
                bfr[jj] = *(const bf16x8*)&Bs[(128 * wc + 16 * jj + lr) * 64 +
                                              (((kk << 2) + quad) ^ (lr & 7)) * 8];
#pragma unroll
            for (int i = 0; i < 4; ++i)
#pragma unroll
                for (int jj = 0; jj < 8; ++jj)
                    acc[i][jj] = __builtin_amdgcn_mfma_f32_16x16x32_bf16(af[i], bfr[jj], acc[i][jj], 0, 0, 0);
        }
    }

#pragma unroll
    for (int i = 0; i < 4; ++i) {
        int row = m0 + 64 * wr + 16 * i + quad * 4;
#pragma unroll
        for (int jj = 0; jj < 8; ++jj) {
            int col = n0 + 128 * wc + 16 * jj + lr;
            float bv = b2f(bias[col]);
#pragma unroll
            for (int r = 0; r < 4; ++r) {
                float v = acc[i][jj][r] + bv;
                if (relu) v = fmaxf(v, 0.f);
                Out[(size_t)(row + r) * ldo + col] = f2b(v);
            }
        }
    }
}

// ---------- encoder attention: per (r,h), fused QKV input (row stride 1536) ----------
// QK^T via MFMA; AV via MFMA (P packed f32->bf16 from Sc; V staged all 32 rows
// with min(row,len-1) clamp -> finite; P cols >= len zeroed so clamped-dup V rows
// contribute exactly 0). Output O row stride 512; rows >= len never stored.
template<int NK>
__device__ __forceinline__ void attn_enc_body(
    const unsigned short* __restrict__ QKV, unsigned short* __restrict__ O,
    int h, int t, int len, int base,
    unsigned short* Qs, unsigned short* Ks, unsigned short* Vs, float (*Sc)[33]) {

#pragma unroll
    for (int it = 0; it < NK; ++it) {       // stage Q,K rows < NK*8 only
        int flat = t + it * 128;
        int row = flat >> 4, ch = flat & 15;
        if (row < len) {
            size_t g = ((size_t)(base + row)) * 1536 + h * DH_ + ch * 8;
            *(uint4*)&Qs[row * 136 + ch * 8] = *(const uint4*)(QKV + g);
            *(uint4*)&Ks[row * 136 + ch * 8] = *(const uint4*)(QKV + g + 512);
        }
    }
#pragma unroll
    for (int it = 0; it < 4; ++it) {        // stage V: ALL 32 rows, clamped (finite)
        int flat = t + it * 128;
        int row = flat >> 4, ch = flat & 15;
        int rr = min(row, len - 1);
        *(uint4*)&Vs[row * 136 + ch * 8] =
            *(const uint4*)(QKV + ((size_t)(base + rr)) * 1536 + 1024 + h * DH_ + ch * 8);
    }
    __syncthreads();

    {   // QK^T via MFMA: wave w owns q rows 16w..16w+15; k-tile 1 only when len>16
        const int wv = t >> 6;
        const int ln_ = t & 63;
        const int quad = ln_ >> 4, lr = ln_ & 15;
        f32x4 a0 = {0.f, 0.f, 0.f, 0.f};
        f32x4 a1 = {0.f, 0.f, 0.f, 0.f};
#pragma unroll
        for (int s = 0; s < 4; ++s) {
            bf16x8 aq = *(const bf16x8*)&Qs[(wv * 16 + lr) * 136 + s * 32 + quad * 8];
            bf16x8 k0 = *(const bf16x8*)&Ks[lr * 136 + s * 32 + quad * 8];
            a0 = __builtin_amdgcn_mfma_f32_16x16x32_bf16(aq, k0, a0, 0, 0, 0);
            if (NK >= 3) {
                bf16x8 k1 = *(const bf16x8*)&Ks[(16 + lr) * 136 + s * 32 + quad * 8];
                a1 = __builtin_amdgcn_mfma_f32_16x16x32_bf16(aq, k1, a1, 0, 0, 0);
            }
        }
        const float scale = 0.08838834764831845f;  // 1/sqrt(128)
#pragma unroll
        for (int reg = 0; reg < 4; ++reg) {
            int q = wv * 16 + quad * 4 + reg;     // C/D: row=(lane>>4)*4+reg, col=lane&15
            Sc[q][lr] = a0[reg] * scale;
            if (NK >= 3) Sc[q][16 + lr] = a1[reg] * scale;
        }
    }
    __syncthreads();

    if (t < 32) {
        if (t < len) {                       // softmax rows < len only
            float mx = -3e38f;
            for (int k = 0; k < len; ++k) mx = fmaxf(mx, Sc[t][k]);
            float sum = 0.f;
            for (int k = 0; k < len; ++k) { float e = __expf(Sc[t][k] - mx); Sc[t][k] = e; sum += e; }
            float inv = 1.f / sum;
            for (int k = 0; k < len; ++k) Sc[t][k] *= inv;
        }
        for (int k = len; k < 32; ++k) Sc[t][k] = 0.f;   // kill garbage cols (all rows)
    }
    __syncthreads();

    {   // AV via MFMA: O = P @ V (one 16x16x32 per 16-col d-fragment; K=32 covers all keys)
        const int wv = t >> 6;
        const int ln_ = t & 63;
        const int quad = ln_ >> 4, lr = ln_ & 15;
        // A-frag: P[16wv+lr][quad*8+e], f32 -> bf16 (RNE)
        union { bf16x8 v; unsigned short u[8]; } af;
        const float* srow = &Sc[16 * wv + lr][quad * 8];
#pragma unroll
        for (int e = 0; e < 8; ++e) af.u[e] = f2b(srow[e]);
        f32x4 o_[8];
#pragma unroll
        for (int nf = 0; nf < 8; ++nf) {
            union { bf16x8 v; unsigned short u[8]; } bfr;
#pragma unroll
            for (int e = 0; e < 8; ++e)
                bfr.u[e] = Vs[(quad * 8 + e) * 136 + nf * 16 + lr];
            f32x4 z = {0.f, 0.f, 0.f, 0.f};
            o_[nf] = __builtin_amdgcn_mfma_f32_16x16x32_bf16(af.v, bfr.v, z, 0, 0, 0);
        }
        const int qb = 16 * wv + quad * 4;
#pragma unroll
        for (int reg = 0; reg < 4; ++reg) {
            int q = qb + reg;                 // C/D: row=quad*4+reg, col=lr
            if (q < len) {
                size_t ga = ((size_t)(base + q)) * C_ + h * DH_;
#pragma unroll
                for (int nf = 0; nf < 8; ++nf)
                    O[ga + nf * 16 + lr] = f2b(o_[nf][reg]);
            }
        }
    }
}

__global__ __launch_bounds__(128)
void attn_enc_kernel(const unsigned short* __restrict__ QKV, unsigned short* __restrict__ O,
                     const int* __restrict__ lens, const int* __restrict__ off) {
    const int r = blockIdx.x, h = blockIdx.y, t = threadIdx.x;
    const int len = lens[r];
    if (len <= 0) return;
    const int base = off[r];
    __shared__ unsigned short Qs[32 * 136], Ks[32 * 136], Vs[32 * 136];
    __shared__ float Sc[32][33];
    switch ((len + 7) >> 3) {                // block-uniform dispatch
        case 1:  attn_enc_body<1>(QKV, O, h, t, len, base, Qs, Ks, Vs, Sc); break;
        case 2:  attn_enc_body<2>(QKV, O, h, t, len, base, Qs, Ks, Vs, Sc); break;
        case 3:  attn_enc_body<3>(QKV, O, h, t, len, base, Qs, Ks, Vs, Sc); break;
        default: attn_enc_body<4>(QKV, O, h, t, len, base, Qs, Ks, Vs, Sc); break;
    }
}

// ---------- PMA attention: per (r,h); shared query row qp[512]; fused KV (stride 1024) ----------
// (R6's GEMM-free variant was 169 us -- scalar projection over scattered Wv rows.
//  Keep the MFMA GEMM for KV; this kernel stays light. Do not re-derive.)
__global__ __launch_bounds__(64)
void attn_pma_kernel(const unsigned short* __restrict__ qp, const unsigned short* __restrict__ KV,
                     unsigned short* __restrict__ O,
                     const int* __restrict__ lens, const int* __restrict__ off) {
    const int r = blockIdx.x, h = blockIdx.y, t = threadIdx.x;
    const int len = lens[r];
    if (len <= 0) return;
    const int base = off[r];
    __shared__ float qv[128];
    __shared__ float attn[32];
    const size_t qb = (size_t)r * C_ + h * DH_;
    qv[t]      = b2f(qp[h * DH_ + t]);
    qv[t + 64] = b2f(qp[h * DH_ + t + 64]);
    __syncthreads();
    if (t < 32 && t < len) {
        const unsigned short* krow = KV + ((size_t)(base + t)) * 1024 + h * DH_;
        float s = 0.f;
        for (int d = 0; d < 128; ++d) s += qv[d] * b2f(krow[d]);
        attn[t] = s * 0.08838834764831845f;
    }
    __syncthreads();
    if (t == 0) {
        float mx = -3e38f;
        for (int k = 0; k < len; ++k) mx = fmaxf(mx, attn[k]);
        float sum = 0.f;
        for (int k = 0; k < len; ++k) { float e = __expf(attn[k] - mx); attn[k] = e; sum += e; }
        float inv = 1.f / sum;
        for (int k = 0; k < len; ++k) attn[k] *= inv;
    }
    __syncthreads();
    float a0 = 0.f, a1 = 0.f;
    for (int k = 0; k < len; ++k) {
        const unsigned short* vrow = KV + ((size_t)(base + k)) * 1024 + 512 + h * DH_;
        float a = attn[k];
        a0 += a * b2f(vrow[t]);
        a1 += a * b2f(vrow[t + 64]);
    }
    O[qb + t]      = f2b(a0);
    O[qb + t + 64] = f2b(a1);
}

// ---------- LayerNorm: 4 rows/block (1 wave each); meta!=null: skip rows >= meta[1] ----------
__global__ __launch_bounds__(256)
void ln_kernel(const unsigned short* __restrict__ A, const unsigned short* __restrict__ Res,
               const unsigned short* __restrict__ gamma, const unsigned short* __restrict__ beta,
               unsigned short* __restrict__ out, const int* __restrict__ lens, int use_mask,
               const int* __restrict__ meta) {
    const int m = blockIdx.x * 4 + (threadIdx.x >> 6);
    if (meta && m >= meta[1]) return;   // wave-uniform; no block barrier in this kernel
    const int lane = threadIdx.x & 63;
    const bool masked = use_mask && ((m & 31) >= lens[m >> 5]);
    const size_t base = (size_t)m * C_ + lane * 8;
    float xa[8], xr[8], x[8];
    unpack8(*(const uint4*)(A + base), xa);
    unpack8(*(const uint4*)(Res + base), xr);
    float s = 0.f, ss = 0.f;
#pragma unroll
    for (int e = 0; e < 8; ++e) {
        x[e] = (masked ? 0.f : xa[e]) + xr[e];
        s += x[e]; ss += x[e] * x[e];
    }
#pragma unroll
    for (int off = 32; off > 0; off >>= 1) {
        s  += __shfl_down(s, off);
        ss += __shfl_down(ss, off);
    }
    s = __shfl(s, 0); ss = __shfl(ss, 0);
    const float mu = s * (1.f / 512.f);
    const float rinv = rsqrtf(fmaxf(ss * (1.f / 512.f) - mu * mu, 0.f) + 1e-5f);
    float gg[8], bb[8], y[8];
    unpack8(*(const uint4*)(gamma + lane * 8), gg);
    unpack8(*(const uint4*)(beta + lane * 8), bb);
#pragma unroll
    for (int e = 0; e < 8; ++e) y[e] = (x[e] - mu) * rinv * gg[e] + bb[e];
    *(uint4*)(out + base) = pack8(y);
}

// ========== fused tail: [Wo2+LN, FF2+LN, Wc+LN, FF3+LN] + final write ==========
// 16 reactions/block, 256 threads. Each matvec: M=16 MFMA 16x16x32 (same verified
// fragment mapping as gemm_bt/QK), W streamed from L2 (0.5 MB, hot across blocks).
// LDS rows padded to 520 shorts -> A-frag reads are 2-way bank (free).
__device__ __forceinline__ void tail_matvec(const unsigned short* cur, unsigned short* tmp,
        const unsigned short* __restrict__ W, const unsigned short* __restrict__ bias,
        int relu, int t) {
    const int w = t >> 6, l = t & 63;
    const int arow = l & 15, kq = l >> 4;
    f32x4 acc[8] = {};
    for (int ks = 0; ks < 16; ++ks) {
        bf16x8 af = *(const bf16x8*)&cur[arow * 520 + ks * 32 + kq * 8];
#pragma unroll
        for (int nf = 0; nf < 8; ++nf) {
            int n = 128 * w + 16 * nf + arow;
            bf16x8 bfr = *(const bf16x8*)&W[(size_t)n * 512 + ks * 32 + kq * 8];
            acc[nf] = __builtin_amdgcn_mfma_f32_16x16x32_bf16(af, bfr, acc[nf], 0, 0, 0);
        }
    }
#pragma unroll
    for (int nf = 0; nf < 8; ++nf) {
        int col = 128 * w + 16 * nf + arow;
        float bv = b2f(bias[col]);
#pragma unroll
        for (int reg = 0; reg < 4; ++reg) {
            float v = acc[nf][reg] + bv;       // C/D: row=kq*4+reg, col=arow-offset
            if (relu) v = fmaxf(v, 0.f);
            tmp[(kq * 4 + reg) * 520 + col] = f2b(v);
        }
    }
}

// LN combine: cur = LN(tmp + (res_seed ? seed : cur); gamma, beta).
__device__ __forceinline__ void tail_ln(unsigned short* cur, const unsigned short* tmp,
        const unsigned short* __restrict__ gamma, const unsigned short* __restrict__ beta,
        const unsigned short* __restrict__ res_seed, int t) {
    const int r = t >> 4, i = t & 15;
    float val[32];
    float s = 0.f, ss = 0.f;
#pragma unroll
    for (int j = 0; j < 32; ++j) {
        int c = i * 32 + j;
        float a = b2f(tmp[r * 520 + c]);
        float b = res_seed ? b2f(res_seed[c]) : b2f(cur[r * 520 + c]);
        float v = a + b;
        val[j] = v; s += v; ss += v * v;
    }
#pragma unroll
    for (int off_ = 8; off_ > 0; off_ >>= 1) {
        s  += __shfl_down(s, off_, 16);
        ss += __shfl_down(ss, off_, 16);
    }
    s = __shfl(s, 0, 16); ss = __shfl(ss, 0, 16);
    const float mu = s * (1.f / 512.f);
    const float rinv = rsqrtf(fmaxf(ss * (1.f / 512.f) - mu * mu, 0.f) + 1e-5f);
#pragma unroll
    for (int j = 0; j < 32; ++j) {
        int c = i * 32 + j;
        float y = (val[j] - mu) * rinv * b2f(gamma[c]) + b2f(beta[c]);
        cur[r * 520 + c] = f2b(y);
    }
}

__global__ __launch_bounds__(256)
void tail_kernel(const unsigned short* __restrict__ S2,
                 const unsigned short* __restrict__ Wo2, const unsigned short* __restrict__ bo2,
                 const unsigned short* __restrict__ Wf2, const unsigned short* __restrict__ fb2,
                 const unsigned short* __restrict__ Wc,  const unsigned short* __restrict__ bc,
                 const unsigned short* __restrict__ Wf3, const unsigned short* __restrict__ fb3,
                 const unsigned short* __restrict__ g12, const unsigned short* __restrict__ b12,
                 const unsigned short* __restrict__ g22, const unsigned short* __restrict__ b22,
                 const unsigned short* __restrict__ g13, const unsigned short* __restrict__ b13,
                 const unsigned short* __restrict__ g23, const unsigned short* __restrict__ b23,
                 const unsigned short* __restrict__ seedv,
                 const int* __restrict__ lens, void* __restrict__ out,
                 const int* __restrict__ flag, size_t elem_off) {
    __shared__ unsigned short cur[16 * 520];
    __shared__ unsigned short tmp[16 * 520];
    const int t = threadIdx.x;
    const int rbase = blockIdx.x * 16;
    const int r = t >> 4, i = t & 15;

#pragma unroll
    for (int j = 0; j < 4; ++j)
        *(uint4*)&cur[r * 520 + i * 32 + j * 8] =
            *(const uint4*)&S2[(size_t)(rbase + r) * 512 + i * 32 + j * 8];
    __syncthreads();

    tail_matvec(cur, tmp, Wo2, bo2, 0, t); __syncthreads();
    tail_ln(cur, tmp, g12, b12, seedv, t); __syncthreads();
    tail_matvec(cur, tmp, Wf2, fb2, 1, t); __syncthreads();
    tail_ln(cur, tmp, g22, b22, nullptr, t); __syncthreads();
    tail_matvec(cur, tmp, Wc, bc, 0, t); __syncthreads();
    tail_ln(cur, tmp, g13, b13, nullptr, t); __syncthreads();
    tail_matvec(cur, tmp, Wf3, fb3, 1, t); __syncthreads();
    tail_ln(cur, tmp, g23, b23, nullptr, t); __syncthreads();

    const int rg = rbase + r;
    const bool ok = lens[rg] > 0;
    if (*flag) {
#pragma unroll
        for (int j = 0; j < 4; ++j) {
            uint4 v = make_uint4(0u, 0u, 0u, 0u);
            if (ok) v = *(uint4*)&cur[r * 520 + i * 32 + j * 8];
            *(uint4*)((unsigned short*)out + elem_off + (size_t)rg * 512 + i * 32 + j * 8) = v;
        }
    } else {
#pragma unroll
        for (int j = 0; j < 4; ++j) {
            float x[8] = {};
            if (ok) unpack8(*(uint4*)&cur[r * 520 + i * 32 + j * 8], x);
            float* o = (float*)out + elem_off + (size_t)rg * 512 + i * 32 + j * 8;
            *(float4*)o       = make_float4(x[0], x[1], x[2], x[3]);
            *(float4*)(o + 4) = make_float4(x[4], x[5], x[6], x[7]);
        }
    }
}

extern "C" void kernel_launch(void* const* d_in, const int* in_sizes, int n_in,
                              void* d_out, int out_size, void* d_ws, size_t ws_size,
                              hipStream_t stream) {
    (void)in_sizes; (void)n_in;
    const void* gene = d_in[0];
    const int*  gidx = (const int*)d_in[1];
    const int*  lens = (const int*)d_in[2];

    // ---- workspace header: flag, meta(2), off[4096] ints ----
    int* ibase = (int*)d_ws;
    int* flag  = ibase;
    int* meta  = ibase + 2;
    int* d_off = ibase + 8;
    unsigned short* ws0 = (unsigned short*)(ibase + 8 + 4096);
    const size_t hdr_bytes = (size_t)(8 + 4096) * 4;

    size_t off = 0;
    auto take = [&](size_t elems) { unsigned short* p = ws0 + off; off += elems; return p; };
    const size_t CC = (size_t)C_ * C_;
    unsigned short* wEnc0 = take(3 * CC);   // [Wq0;Wk0;Wv0]  (1536 x 512)
    unsigned short* wEnc1 = take(3 * CC);   // [Wq1;Wk1;Wv1]
    unsigned short* wKVp  = take(2 * CC);   // [Wk2;Wv2]      (1024 x 512)
    unsigned short* wO  = take(4 * CC);
    unsigned short* wF  = take(4 * CC);
    unsigned short* wP  = take(CC);
    unsigned short* wQp = take(CC);         // Wq2
    unsigned short* wVd = take(CC);         // Wv3
    unsigned short* wWc = take(CC);         // Wo3 @ Wv3 (decoder collapse)
    unsigned short* cbq = take(4 * C_);
    unsigned short* cbk = take(4 * C_);
    unsigned short* cbv = take(4 * C_);
    unsigned short* cbo = take(4 * C_);
    unsigned short* cff = take(4 * C_);
    unsigned short* cg1 = take(4 * C_);
    unsigned short* cb1 = take(4 * C_);
    unsigned short* cg2 = take(4 * C_);
    unsigned short* cb2 = take(4 * C_);
    unsigned short* cpb = take(C_);
    unsigned short* csd = take(C_);
    unsigned short* bqkv0 = take(3 * C_);
    unsigned short* bqkv1 = take(3 * C_);
    unsigned short* bkv2  = take(2 * C_);
    unsigned short* bcb   = take(C_);       // Wo3 bv3 + bo3
    unsigned short* qp    = take(C_);
    const size_t wbytes = hdr_bytes + off * 2;

    // per-reaction: X(32*512) + AQKV(32*1536) + Aout(32*512) + S2(512) elems
    const size_t per_r = ((size_t)32 * 2560 + 512) * 2;
    int Rc = 0;
    const int cands[6] = {4096, 2048, 1024, 512, 256, 128};
    for (int i = 0; i < 6; ++i) {
        size_t need = wbytes + (size_t)cands[i] * per_r;
        if (need <= ws_size) { Rc = cands[i]; break; }
    }
    if (Rc == 0) {
        diag_kernel<<<(out_size + 255) / 256, 256, 0, stream>>>(
            (unsigned short*)d_out, out_size, 1000.0f + (float)(ws_size >> 20));
        return;
    }
    const int Mc = Rc * 32;

    unsigned short* X    = take((size_t)Mc * C_);
    unsigned short* AQKV = take((size_t)Mc * 1536);
    unsigned short* Aout = take((size_t)Mc * C_);
    unsigned short* S2 = take((size_t)Rc * C_);

    detect_kernel<<<1, 256, 0, stream>>>((const unsigned short*)gene, flag);
    auto cvt = [&](const void* in, unsigned short* out_, int n, int src_off) {
        cvt_any_kernel<<<(n + 2047) / 2048, 256, 0, stream>>>(in, out_, n, flag, src_off);
    };
    // encoder QKV concats (blocks 0,1)
    cvt(d_in[3], wEnc0,          (int)CC, 0);
    cvt(d_in[4], wEnc0 + CC,     (int)CC, 0);
    cvt(d_in[5], wEnc0 + 2 * CC, (int)CC, 0);
    cvt(d_in[3], wEnc1,          (int)CC, (int)CC);
    cvt(d_in[4], wEnc1 + CC,     (int)CC, (int)CC);
    cvt(d_in[5], wEnc1 + 2 * CC, (int)CC, (int)CC);
    // PMA KV concat (block 2), PMA Wq, dec Wv (block 3)
    cvt(d_in[4], wKVp,      (int)CC, (int)(2 * CC));
    cvt(d_in[5], wKVp + CC, (int)CC, (int)(2 * CC));
    cvt(d_in[3], wQp, (int)CC, (int)(2 * CC));
    cvt(d_in[5], wVd, (int)CC, (int)(3 * CC));
    cvt(d_in[6], wO, (int)(4 * CC), 0);
    cvt(d_in[7], wF, (int)(4 * CC), 0);
    cvt(d_in[17], wP, (int)CC, 0);
    cvt(d_in[8],  cbq, 4 * C_, 0); cvt(d_in[9],  cbk, 4 * C_, 0); cvt(d_in[10], cbv, 4 * C_, 0);
    cvt(d_in[11], cbo, 4 * C_, 0); cvt(d_in[12], cff, 4 * C_, 0);
    cvt(d_in[13], cg1, 4 * C_, 0); cvt(d_in[14], cb1, 4 * C_, 0);
    cvt(d_in[15], cg2, 4 * C_, 0); cvt(d_in[16], cb2, 4 * C_, 0);
    cvt(d_in[18], cpb, C_, 0);     cvt(d_in[19], csd, C_, 0);
    bias_concat_kernel<<<1, 256, 0, stream>>>(cbq, cbk, cbv, bqkv0, bqkv1, bkv2);
    qp_kernel<<<1, 256, 0, stream>>>(wQp, cbq + 2 * C_, csd, qp);
    wc_kernel<<<512, 256, 0, stream>>>(wO + 3 * CC, wVd, wWc);
    bc_kernel<<<2, 256, 0, stream>>>(wO + 3 * CC, cbv + 3 * C_, cbo + 3 * C_, bcb);

    auto gemm = [&](auto nt_tag, const unsigned short* Ain, const unsigned short* Win,
                    const unsigned short* bias, unsigned short* Outp, int Mrows, int relu,
                    const int* mt) {
        constexpr int NT = decltype(nt_tag)::value;
        const int MT = Mrows / 128;
        const int grid = 8 * ((MT + 7) / 8) * NT;
        gemm_bt_kernel<NT><<<dim3(grid), 256, 0, stream>>>(Ain, Win, bias, Outp, relu, mt, MT);
    };
    using N2 = std::integral_constant<int, 2>;
    using N4 = std::integral_constant<int, 4>;
    using N6 = std::integral_constant<int, 6>;

    for (int c = 0; c < R_ / Rc; ++c) {
        const int r0 = c * Rc;
        const int* lc = lens + r0;

        scan_kernel<<<1, 256, 0, stream>>>(lc, d_off, meta, Rc);
        gather_kernel<<<Mc * 64 / 256, 256, 0, stream>>>(
            gene, gidx + (size_t)r0 * L_, lc, d_off, X, flag);
        ztail_kernel<<<32, 256, 0, stream>>>(X, meta);

        for (int i = 0; i < 2; ++i) {
            gemm(N6{}, X, i ? wEnc1 : wEnc0, i ? bqkv1 : bqkv0, AQKV, Mc, 0, meta);
            attn_enc_kernel<<<dim3(Rc, H_), 128, 0, stream>>>(AQKV, Aout, lc, d_off);
            gemm(N2{}, Aout, wO + (size_t)i * CC, cbo + i * C_, AQKV, Mc, 0, meta);  // reuse AQKV as tmp
            ln_kernel<<<Mc / 4, 256, 0, stream>>>(AQKV, X, cg1 + i * C_, cb1 + i * C_, X, lc, 0, meta);
            gemm(N2{}, X, wF + (size_t)i * CC, cff + i * C_, Aout, Mc, 1, meta);
            ln_kernel<<<Mc / 4, 256, 0, stream>>>(Aout, X, cg2 + i * C_, cb2 + i * C_, X, lc, 0, meta);
        }

        gemm(N2{}, X, wP, cpb, Aout, Mc, 1, meta);                // Y = relu(X Wp + bp)

        // PMA: KV via MFMA GEMM (proven), light attention kernel
        gemm(N4{}, Aout, wKVp, bkv2, AQKV, Mc, 0, meta);          // fused K|V (stride 1024)
        attn_pma_kernel<<<dim3(Rc, H_), 64, 0, stream>>>(qp, AQKV, S2, lc, d_off);

        // fused tail: Wo2+LN, FF2+LN, Wc+LN, FF3+LN, final write
        tail_kernel<<<Rc / 16, 256, 0, stream>>>(
            S2,
            wO + 2 * CC, cbo + 2 * C_,
            wF + 2 * CC, cff + 2 * C_,
            wWc, bcb,
            wF + 3 * CC, cff + 3 * C_,
            cg1 + 2 * C_, cb1 + 2 * C_, cg2 + 2 * C_, cb2 + 2 * C_,
            cg1 + 3 * C_, cb1 + 3 * C_, cg2 + 3 * C_, cb2 + 3 * C_,
            csd, lc, d_out, flag, (size_t)r0 * C_);
    }
}

// Round 11
// 1657.791 us; speedup vs baseline: 1.3638x; 1.3638x over previous
//
#include <hip/hip_runtime.h>
#include <stdint.h>

#define R_ 4096
#define L_ 32
#define C_ 512
#define H_ 4
#define DH_ 128

typedef __bf16 bf16x8 __attribute__((ext_vector_type(8)));
typedef float f32x4 __attribute__((ext_vector_type(4)));

// ---------- bf16 bit helpers (RNE) ----------
__device__ __forceinline__ float b2f(unsigned int u) {
    union { unsigned int i; float f; } x; x.i = u << 16; return x.f;
}
__device__ __forceinline__ unsigned short f2b(float f) {
    union { float f; unsigned int i; } x; x.f = f;
    unsigned int i = x.i;
    i += 0x7fffu + ((i >> 16) & 1u);
    return (unsigned short)(i >> 16);
}
__device__ __forceinline__ void unpack8(uint4 v, float* x) {
    x[0] = b2f(v.x & 0xffffu); x[1] = b2f(v.x >> 16);
    x[2] = b2f(v.y & 0xffffu); x[3] = b2f(v.y >> 16);
    x[4] = b2f(v.z & 0xffffu); x[5] = b2f(v.z >> 16);
    x[6] = b2f(v.w & 0xffffu); x[7] = b2f(v.w >> 16);
}
__device__ __forceinline__ uint4 pack8(const float* x) {
    uint4 v;
    v.x = (unsigned)f2b(x[0]) | ((unsigned)f2b(x[1]) << 16);
    v.y = (unsigned)f2b(x[2]) | ((unsigned)f2b(x[3]) << 16);
    v.z = (unsigned)f2b(x[4]) | ((unsigned)f2b(x[5]) << 16);
    v.w = (unsigned)f2b(x[6]) | ((unsigned)f2b(x[7]) << 16);
    return v;
}

// async global->LDS, 16B per lane; LDS dest = wave-uniform base + lane*16
__device__ __forceinline__ void gload_lds16(const unsigned short* g, unsigned short* l) {
    __builtin_amdgcn_global_load_lds(
        (const __attribute__((address_space(1))) void*)g,
        (__attribute__((address_space(3))) void*)l, 16, 0, 0);
}

// ---------- dtype detection: 1 = bf16, 0 = fp32 ----------
__global__ __launch_bounds__(256)
void detect_kernel(const unsigned short* __restrict__ gene, int* __restrict__ flag) {
    __shared__ int cnt;
    if (threadIdx.x == 0) cnt = 0;
    __syncthreads();
    int local = 0;
    for (int j = 0; j < 8; ++j) {
        int i = threadIdx.x * 8 + j;
        unsigned short u = gene[2 * i];
        int e = (u >> 7) & 0xFF;
        if (e >= 100 && e <= 140) ++local;
    }
    atomicAdd(&cnt, local);
    __syncthreads();
    if (threadIdx.x == 0) *flag = (cnt >= 1024) ? 1 : 0;
}

// ---------- convert (fp32|bf16) -> bf16 with source element offset ----------
__global__ __launch_bounds__(256)
void cvt_any_kernel(const void* __restrict__ in, unsigned short* __restrict__ out,
                    int n, const int* __restrict__ flag, int src_off) {
    int i0 = (blockIdx.x * 256 + threadIdx.x) * 8;
    if (i0 >= n) return;
    if (*flag) {
        *(uint4*)(out + i0) = *(const uint4*)((const unsigned short*)in + src_off + i0);
    } else {
        const float* f = (const float*)in + src_off;
        float4 a = *(const float4*)(f + i0);
        float4 b = *(const float4*)(f + i0 + 4);
        float x[8] = {a.x, a.y, a.z, a.w, b.x, b.y, b.z, b.w};
        *(uint4*)(out + i0) = pack8(x);
    }
}

// ---------- concat biases: bqkv0/1 [1536], bkv2 [1024] from cbq/cbk/cbv ----------
__global__ __launch_bounds__(256)
void bias_concat_kernel(const unsigned short* __restrict__ bq, const unsigned short* __restrict__ bk,
                        const unsigned short* __restrict__ bv,
                        unsigned short* __restrict__ bqkv0, unsigned short* __restrict__ bqkv1,
                        unsigned short* __restrict__ bkv2) {
    int t = threadIdx.x;
#pragma unroll
    for (int s = 0; s < 2; ++s) {
        int i = t + s * 256;
        bqkv0[i]        = bq[i];
        bqkv0[i + 512]  = bk[i];
        bqkv0[i + 1024] = bv[i];
        bqkv1[i]        = bq[i + 512];
        bqkv1[i + 512]  = bk[i + 512];
        bqkv1[i + 1024] = bv[i + 512];
        bkv2[i]         = bk[i + 1024];
        bkv2[i + 512]   = bv[i + 1024];
    }
}

// ---------- PMA query: qp[512] = Wq2 . seed + bq2 (seed is broadcast -> one row) ----------
__global__ __launch_bounds__(256)
void qp_kernel(const unsigned short* __restrict__ Wq2, const unsigned short* __restrict__ bq2,
               const unsigned short* __restrict__ seed, unsigned short* __restrict__ qp) {
    __shared__ float sv[512];
    int t = threadIdx.x;
    sv[t] = b2f(seed[t]); sv[t + 256] = b2f(seed[t + 256]);
    __syncthreads();
#pragma unroll
    for (int s = 0; s < 2; ++s) {
        int n = t + s * 256;
        const unsigned short* wrow = Wq2 + (size_t)n * 512;
        float acc = 0.f;
        for (int k8 = 0; k8 < 64; ++k8) {
            float x[8];
            unpack8(*(const uint4*)(wrow + k8 * 8), x);
#pragma unroll
            for (int e = 0; e < 8; ++e) acc += x[e] * sv[k8 * 8 + e];
        }
        qp[n] = f2b(acc + b2f(bq2[n]));
    }
}

// ---------- Wc = Wo3 @ Wv3 (decoder collapse: softmax over 1 key == identity) ----------
__global__ __launch_bounds__(256)
void wc_kernel(const unsigned short* __restrict__ Wo3, const unsigned short* __restrict__ Wv3,
               unsigned short* __restrict__ Wc) {
    const int i = blockIdx.x, t = threadIdx.x;
    __shared__ float wo[512];
    wo[t] = b2f(Wo3[(size_t)i * 512 + t]);
    wo[t + 256] = b2f(Wo3[(size_t)i * 512 + t + 256]);
    __syncthreads();
    float a0 = 0.f, a1 = 0.f;
    for (int d = 0; d < 512; ++d) {
        const unsigned short* row = Wv3 + (size_t)d * 512;
        float w = wo[d];
        a0 += w * b2f(row[t]);
        a1 += w * b2f(row[t + 256]);
    }
    Wc[(size_t)i * 512 + t]       = f2b(a0);
    Wc[(size_t)i * 512 + t + 256] = f2b(a1);
}

// ---------- bc = Wo3 @ bv3 + bo3 ----------
__global__ __launch_bounds__(256)
void bc_kernel(const unsigned short* __restrict__ Wo3, const unsigned short* __restrict__ bv3,
               const unsigned short* __restrict__ bo3, unsigned short* __restrict__ bc) {
    const int t = threadIdx.x;
    __shared__ float bvv[512];
    bvv[t] = b2f(bv3[t]); bvv[t + 256] = b2f(bv3[t + 256]);
    __syncthreads();
    const int i = blockIdx.x * 256 + t;
    const unsigned short* row = Wo3 + (size_t)i * 512;
    float acc = 0.f;
    for (int d8 = 0; d8 < 64; ++d8) {
        float x[8];
        unpack8(*(const uint4*)(row + d8 * 8), x);
#pragma unroll
        for (int e = 0; e < 8; ++e) acc += x[e] * bvv[d8 * 8 + e];
    }
    bc[i] = f2b(acc + b2f(bo3[i]));
}

// ---------- diagnostic ----------
__global__ __launch_bounds__(256)
void diag_kernel(unsigned short* __restrict__ out, int n, float val) {
    int i = blockIdx.x * 256 + threadIdx.x;
    if (i < n) out[i] = f2b(val);
}

// ---------- exclusive scan of lens -> off; meta[0]=total, meta[1]=totalPad(128) ----------
__global__ __launch_bounds__(256)
void scan_kernel(const int* __restrict__ lens, int* __restrict__ off,
                 int* __restrict__ meta, int Rc) {
    __shared__ int tsum[257];
    const int t = threadIdx.x;
    const int chunk = (Rc + 255) / 256;
    const int lo = t * chunk;
    const int hi = min(lo + chunk, Rc);
    int s = 0;
    for (int i = lo; i < hi; ++i) {
        int l = lens[i]; l = max(0, min(32, l));
        s += l;
    }
    tsum[t] = s;
    __syncthreads();
    if (t == 0) {
        int acc = 0;
        for (int i = 0; i < 256; ++i) { int v = tsum[i]; tsum[i] = acc; acc += v; }
        tsum[256] = acc;
        meta[0] = acc;
        meta[1] = (acc + 127) & ~127;
    }
    __syncthreads();
    int run = tsum[t];
    for (int i = lo; i < hi; ++i) {
        off[i] = run;
        int l = lens[i]; l = max(0, min(32, l));
        run += l;
    }
}

// ---------- gather genes -> compacted X rows [off[r]+j], j<len[r] ----------
__global__ __launch_bounds__(256)
void gather_kernel(const void* __restrict__ gene_v, const int* __restrict__ gidx,
                   const int* __restrict__ lens, const int* __restrict__ off,
                   unsigned short* __restrict__ X, const int* __restrict__ flag) {
    int tid = blockIdx.x * 256 + threadIdx.x;
    int m = tid >> 6;
    int ch = tid & 63;
    int r = m >> 5, j = m & 31;
    if (j >= lens[r]) return;
    size_t dst = (size_t)(off[r] + j) * C_ + ch * 8;
    size_t base = (size_t)gidx[m] * C_ + ch * 8;
    uint4 v;
    if (*flag) {
        v = *(const uint4*)((const unsigned short*)gene_v + base);
    } else {
        const float* f = (const float*)gene_v;
        float4 a = *(const float4*)(f + base);
        float4 b = *(const float4*)(f + base + 4);
        float x[8] = {a.x, a.y, a.z, a.w, b.x, b.y, b.z, b.w};
        v = pack8(x);
    }
    *(uint4*)(X + dst) = v;
}

// ---------- zero pad rows total..totalPad-1 (<=127 rows); grid 32 blocks ----------
__global__ __launch_bounds__(256)
void ztail_kernel(unsigned short* __restrict__ X, const int* __restrict__ meta) {
    int tid = blockIdx.x * 256 + threadIdx.x;
    int m = meta[0] + (tid >> 6);
    int ch = tid & 63;
    if (m < meta[1])
        *(uint4*)(X + (size_t)m * C_ + ch * 8) = make_uint4(0u, 0u, 0u, 0u);
}

// ---------- GEMM: Out[M, NT*256] = A @ W^T + bias, opt ReLU ----------
// R3-proven structure: 128x256 tile, BK=64 (8 K-iters), single-buffer LDS,
// XOR-swizzled (both-sides involution), global_load_lds 16B staging.
// (R4's explicit 2-phase dbuf regressed 15-20% -- do not re-add.)
// (R9: __launch_bounds__(256,3) regressed 1.9x -- 84 VGPR + 3 blocks/CU thrashed
//  L2 (WRITE_SIZE 103->357 MB). KEEP (256,2). The XCD decode depends on the
//  2-block/CU L2 residency window.)
template<int NT>
__global__ __launch_bounds__(256, 2)
void gemm_bt_kernel(const unsigned short* __restrict__ A, const unsigned short* __restrict__ W,
                    const unsigned short* __restrict__ bias, unsigned short* __restrict__ Out,
                    int relu, const int* __restrict__ meta, int MT) {
    const int b = blockIdx.x;
    const int xcd = b & 7;
    const int j = b >> 3;
    const int ml = j / NT;
    const int n = j - ml * NT;
    const int m = ml * 8 + xcd;
    if (m >= MT) return;
    const int m0 = m * 128, n0 = n * 256;
    if (meta && m0 >= meta[1]) return;   // block-uniform, before any barrier
    const int ldo = NT * 256;

    __shared__ unsigned short As[128 * 64];
    __shared__ unsigned short Bs[256 * 64];

    const int t = threadIdx.x;
    const int wave = t >> 6, lane = t & 63;
    const int quad = lane >> 4, lr = lane & 15;
    const int wr = wave >> 1, wc = wave & 1;

    // staging: lane covers row (l>>3), 16B chunk col8 = (l&7) ^ (l>>3)
    // (pre-swizzled global source, linear LDS dest)
    const int srow8 = lane >> 3;
    const int scol8 = (lane & 7) ^ srow8;
    const unsigned short* gaB = A + (size_t)(m0 + wave * 8 + srow8) * C_ + scol8 * 8;
    const unsigned short* gbB = W + (size_t)(n0 + wave * 8 + srow8) * C_ + scol8 * 8;
    unsigned short* lA = As + wave * 512;
    unsigned short* lB = Bs + wave * 512;

    f32x4 acc[4][8] = {};

    for (int k0 = 0; k0 < C_; k0 += 64) {
        __syncthreads();
#pragma unroll
        for (int jj = 0; jj < 4; ++jj)
            gload_lds16(gaB + (size_t)jj * 32 * C_ + k0, lA + jj * 2048);
#pragma unroll
        for (int jj = 0; jj < 8; ++jj)
            gload_lds16(gbB + (size_t)jj * 32 * C_ + k0, lB + jj * 2048);
        __syncthreads();

#pragma unroll
        for (int kk = 0; kk < 2; ++kk) {
            bf16x8 af[4], bfr[8];
#pragma unroll
            for (int i = 0; i < 4; ++i)
                af[i] = *(const bf16x8*)&As[(64 * wr + 16 * i + lr) * 64 +
                                            (((kk << 2) + quad) ^ (lr & 7)) * 8];
#pragma unroll
            for (int jj = 0; jj < 8; ++jj)
                bfr[jj] = *(const bf16x8*)&Bs[(128 * wc + 16 * jj + lr) * 64 +
                                              (((kk << 2) + quad) ^ (lr & 7)) * 8];
#pragma unroll
            for (int i = 0; i < 4; ++i)
#pragma unroll
                for (int jj = 0; jj < 8; ++jj)
                    acc[i][jj] = __builtin_amdgcn_mfma_f32_16x16x32_bf16(af[i], bfr[jj], acc[i][jj], 0, 0, 0);
        }
    }

#pragma unroll
    for (int i = 0; i < 4; ++i) {
        int row = m0 + 64 * wr + 16 * i + quad * 4;
#pragma unroll
        for (int jj = 0; jj < 8; ++jj) {
            int col = n0 + 128 * wc + 16 * jj + lr;
            float bv = b2f(bias[col]);
#pragma unroll
            for (int r = 0; r < 4; ++r) {
                float v = acc[i][jj][r] + bv;
                if (relu) v = fmaxf(v, 0.f);
                Out[(size_t)(row + r) * ldo + col] = f2b(v);
            }
        }
    }
}

// ---------- encoder attention: per (r,h), fused QKV input (row stride 1536) ----------
// QK^T via MFMA; AV via MFMA (P packed f32->bf16 from Sc; V staged all 32 rows
// with min(row,len-1) clamp -> finite; P cols >= len zeroed so clamped-dup V rows
// contribute exactly 0). Output O row stride 512; rows >= len never stored.
template<int NK>
__device__ __forceinline__ void attn_enc_body(
    const unsigned short* __restrict__ QKV, unsigned short* __restrict__ O,
    int h, int t, int len, int base,
    unsigned short* Qs, unsigned short* Ks, unsigned short* Vs, float (*Sc)[33]) {

#pragma unroll
    for (int it = 0; it < NK; ++it) {       // stage Q,K rows < NK*8 only
        int flat = t + it * 128;
        int row = flat >> 4, ch = flat & 15;
        if (row < len) {
            size_t g = ((size_t)(base + row)) * 1536 + h * DH_ + ch * 8;
            *(uint4*)&Qs[row * 136 + ch * 8] = *(const uint4*)(QKV + g);
            *(uint4*)&Ks[row * 136 + ch * 8] = *(const uint4*)(QKV + g + 512);
        }
    }
#pragma unroll
    for (int it = 0; it < 4; ++it) {        // stage V: ALL 32 rows, clamped (finite)
        int flat = t + it * 128;
        int row = flat >> 4, ch = flat & 15;
        int rr = min(row, len - 1);
        *(uint4*)&Vs[row * 136 + ch * 8] =
            *(const uint4*)(QKV + ((size_t)(base + rr)) * 1536 + 1024 + h * DH_ + ch * 8);
    }
    __syncthreads();

    {   // QK^T via MFMA: wave w owns q rows 16w..16w+15; k-tile 1 only when len>16
        const int wv = t >> 6;
        const int ln_ = t & 63;
        const int quad = ln_ >> 4, lr = ln_ & 15;
        f32x4 a0 = {0.f, 0.f, 0.f, 0.f};
        f32x4 a1 = {0.f, 0.f, 0.f, 0.f};
#pragma unroll
        for (int s = 0; s < 4; ++s) {
            bf16x8 aq = *(const bf16x8*)&Qs[(wv * 16 + lr) * 136 + s * 32 + quad * 8];
            bf16x8 k0 = *(const bf16x8*)&Ks[lr * 136 + s * 32 + quad * 8];
            a0 = __builtin_amdgcn_mfma_f32_16x16x32_bf16(aq, k0, a0, 0, 0, 0);
            if (NK >= 3) {
                bf16x8 k1 = *(const bf16x8*)&Ks[(16 + lr) * 136 + s * 32 + quad * 8];
                a1 = __builtin_amdgcn_mfma_f32_16x16x32_bf16(aq, k1, a1, 0, 0, 0);
            }
        }
        const float scale = 0.08838834764831845f;  // 1/sqrt(128)
#pragma unroll
        for (int reg = 0; reg < 4; ++reg) {
            int q = wv * 16 + quad * 4 + reg;     // C/D: row=(lane>>4)*4+reg, col=lane&15
            Sc[q][lr] = a0[reg] * scale;
            if (NK >= 3) Sc[q][16 + lr] = a1[reg] * scale;
        }
    }
    __syncthreads();

    if (t < 32) {
        if (t < len) {                       // softmax rows < len only
            float mx = -3e38f;
            for (int k = 0; k < len; ++k) mx = fmaxf(mx, Sc[t][k]);
            float sum = 0.f;
            for (int k = 0; k < len; ++k) { float e = __expf(Sc[t][k] - mx); Sc[t][k] = e; sum += e; }
            float inv = 1.f / sum;
            for (int k = 0; k < len; ++k) Sc[t][k] *= inv;
        }
        for (int k = len; k < 32; ++k) Sc[t][k] = 0.f;   // kill garbage cols (all rows)
    }
    __syncthreads();

    {   // AV via MFMA: O = P @ V (one 16x16x32 per 16-col d-fragment; K=32 covers all keys)
        const int wv = t >> 6;
        const int ln_ = t & 63;
        const int quad = ln_ >> 4, lr = ln_ & 15;
        // A-frag: P[16wv+lr][quad*8+e], f32 -> bf16 (RNE)
        union { bf16x8 v; unsigned short u[8]; } af;
        const float* srow = &Sc[16 * wv + lr][quad * 8];
#pragma unroll
        for (int e = 0; e < 8; ++e) af.u[e] = f2b(srow[e]);
        f32x4 o_[8];
#pragma unroll
        for (int nf = 0; nf < 8; ++nf) {
            union { bf16x8 v; unsigned short u[8]; } bfr;
#pragma unroll
            for (int e = 0; e < 8; ++e)
                bfr.u[e] = Vs[(quad * 8 + e) * 136 + nf * 16 + lr];
            f32x4 z = {0.f, 0.f, 0.f, 0.f};
            o_[nf] = __builtin_amdgcn_mfma_f32_16x16x32_bf16(af.v, bfr.v, z, 0, 0, 0);
        }
        const int qb = 16 * wv + quad * 4;
#pragma unroll
        for (int reg = 0; reg < 4; ++reg) {
            int q = qb + reg;                 // C/D: row=quad*4+reg, col=lr
            if (q < len) {
                size_t ga = ((size_t)(base + q)) * C_ + h * DH_;
#pragma unroll
                for (int nf = 0; nf < 8; ++nf)
                    O[ga + nf * 16 + lr] = f2b(o_[nf][reg]);
            }
        }
    }
}

__global__ __launch_bounds__(128)
void attn_enc_kernel(const unsigned short* __restrict__ QKV, unsigned short* __restrict__ O,
                     const int* __restrict__ lens, const int* __restrict__ off) {
    const int r = blockIdx.x, h = blockIdx.y, t = threadIdx.x;
    const int len = lens[r];
    if (len <= 0) return;
    const int base = off[r];
    __shared__ unsigned short Qs[32 * 136], Ks[32 * 136], Vs[32 * 136];
    __shared__ float Sc[32][33];
    switch ((len + 7) >> 3) {                // block-uniform dispatch
        case 1:  attn_enc_body<1>(QKV, O, h, t, len, base, Qs, Ks, Vs, Sc); break;
        case 2:  attn_enc_body<2>(QKV, O, h, t, len, base, Qs, Ks, Vs, Sc); break;
        case 3:  attn_enc_body<3>(QKV, O, h, t, len, base, Qs, Ks, Vs, Sc); break;
        default: attn_enc_body<4>(QKV, O, h, t, len, base, Qs, Ks, Vs, Sc); break;
    }
}

// ---------- PMA attention: per (r,h); shared query row qp[512]; fused KV (stride 1024) ----------
// (R6's GEMM-free variant was 169 us -- scalar projection over scattered Wv rows.
//  Keep the MFMA GEMM for KV; this kernel stays light. Do not re-derive.)
__global__ __launch_bounds__(64)
void attn_pma_kernel(const unsigned short* __restrict__ qp, const unsigned short* __restrict__ KV,
                     unsigned short* __restrict__ O,
                     const int* __restrict__ lens, const int* __restrict__ off) {
    const int r = blockIdx.x, h = blockIdx.y, t = threadIdx.x;
    const int len = lens[r];
    if (len <= 0) return;
    const int base = off[r];
    __shared__ float qv[128];
    __shared__ float attn[32];
    const size_t qb = (size_t)r * C_ + h * DH_;
    qv[t]      = b2f(qp[h * DH_ + t]);
    qv[t + 64] = b2f(qp[h * DH_ + t + 64]);
    __syncthreads();
    if (t < 32 && t < len) {
        const unsigned short* krow = KV + ((size_t)(base + t)) * 1024 + h * DH_;
        float s = 0.f;
        for (int d = 0; d < 128; ++d) s += qv[d] * b2f(krow[d]);
        attn[t] = s * 0.08838834764831845f;
    }
    __syncthreads();
    if (t == 0) {
        float mx = -3e38f;
        for (int k = 0; k < len; ++k) mx = fmaxf(mx, attn[k]);
        float sum = 0.f;
        for (int k = 0; k < len; ++k) { float e = __expf(attn[k] - mx); attn[k] = e; sum += e; }
        float inv = 1.f / sum;
        for (int k = 0; k < len; ++k) attn[k] *= inv;
    }
    __syncthreads();
    float a0 = 0.f, a1 = 0.f;
    for (int k = 0; k < len; ++k) {
        const unsigned short* vrow = KV + ((size_t)(base + k)) * 1024 + 512 + h * DH_;
        float a = attn[k];
        a0 += a * b2f(vrow[t]);
        a1 += a * b2f(vrow[t + 64]);
    }
    O[qb + t]      = f2b(a0);
    O[qb + t + 64] = f2b(a1);
}

// ---------- LayerNorm: 4 rows/block (1 wave each); meta!=null: skip rows >= meta[1] ----------
__global__ __launch_bounds__(256)
void ln_kernel(const unsigned short* __restrict__ A, const unsigned short* __restrict__ Res,
               const unsigned short* __restrict__ gamma, const unsigned short* __restrict__ beta,
               unsigned short* __restrict__ out, const int* __restrict__ lens, int use_mask,
               const int* __restrict__ meta) {
    const int m = blockIdx.x * 4 + (threadIdx.x >> 6);
    if (meta && m >= meta[1]) return;   // wave-uniform; no block barrier in this kernel
    const int lane = threadIdx.x & 63;
    const bool masked = use_mask && ((m & 31) >= lens[m >> 5]);
    const size_t base = (size_t)m * C_ + lane * 8;
    float xa[8], xr[8], x[8];
    unpack8(*(const uint4*)(A + base), xa);
    unpack8(*(const uint4*)(Res + base), xr);
    float s = 0.f, ss = 0.f;
#pragma unroll
    for (int e = 0; e < 8; ++e) {
        x[e] = (masked ? 0.f : xa[e]) + xr[e];
        s += x[e]; ss += x[e] * x[e];
    }
#pragma unroll
    for (int off = 32; off > 0; off >>= 1) {
        s  += __shfl_down(s, off);
        ss += __shfl_down(ss, off);
    }
    s = __shfl(s, 0); ss = __shfl(ss, 0);
    const float mu = s * (1.f / 512.f);
    const float rinv = rsqrtf(fmaxf(ss * (1.f / 512.f) - mu * mu, 0.f) + 1e-5f);
    float gg[8], bb[8], y[8];
    unpack8(*(const uint4*)(gamma + lane * 8), gg);
    unpack8(*(const uint4*)(beta + lane * 8), bb);
#pragma unroll
    for (int e = 0; e < 8; ++e) y[e] = (x[e] - mu) * rinv * gg[e] + bb[e];
    *(uint4*)(out + base) = pack8(y);
}

// ========== fused tail: [Wo2+LN, FF2+LN, Wc+LN, FF3+LN] + final write ==========
// 16 reactions/block, 256 threads. Each matvec: M=16 MFMA 16x16x32 (same verified
// fragment mapping as gemm_bt/QK), W streamed from L2 (0.5 MB, hot across blocks).
// LDS rows padded to 520 shorts -> A-frag reads are 2-way bank (free).
__device__ __forceinline__ void tail_matvec(const unsigned short* cur, unsigned short* tmp,
        const unsigned short* __restrict__ W, const unsigned short* __restrict__ bias,
        int relu, int t) {
    const int w = t >> 6, l = t & 63;
    const int arow = l & 15, kq = l >> 4;
    f32x4 acc[8] = {};
    for (int ks = 0; ks < 16; ++ks) {
        bf16x8 af = *(const bf16x8*)&cur[arow * 520 + ks * 32 + kq * 8];
#pragma unroll
        for (int nf = 0; nf < 8; ++nf) {
            int n = 128 * w + 16 * nf + arow;
            bf16x8 bfr = *(const bf16x8*)&W[(size_t)n * 512 + ks * 32 + kq * 8];
            acc[nf] = __builtin_amdgcn_mfma_f32_16x16x32_bf16(af, bfr, acc[nf], 0, 0, 0);
        }
    }
#pragma unroll
    for (int nf = 0; nf < 8; ++nf) {
        int col = 128 * w + 16 * nf + arow;
        float bv = b2f(bias[col]);
#pragma unroll
        for (int reg = 0; reg < 4; ++reg) {
            float v = acc[nf][reg] + bv;       // C/D: row=kq*4+reg, col=arow-offset
            if (relu) v = fmaxf(v, 0.f);
            tmp[(kq * 4 + reg) * 520 + col] = f2b(v);
        }
    }
}

// LN combine: cur = LN(tmp + (res_seed ? seed : cur); gamma, beta).
__device__ __forceinline__ void tail_ln(unsigned short* cur, const unsigned short* tmp,
        const unsigned short* __restrict__ gamma, const unsigned short* __restrict__ beta,
        const unsigned short* __restrict__ res_seed, int t) {
    const int r = t >> 4, i = t & 15;
    float val[32];
    float s = 0.f, ss = 0.f;
#pragma unroll
    for (int j = 0; j < 32; ++j) {
        int c = i * 32 + j;
        float a = b2f(tmp[r * 520 + c]);
        float b = res_seed ? b2f(res_seed[c]) : b2f(cur[r * 520 + c]);
        float v = a + b;
        val[j] = v; s += v; ss += v * v;
    }
#pragma unroll
    for (int off_ = 8; off_ > 0; off_ >>= 1) {
        s  += __shfl_down(s, off_, 16);
        ss += __shfl_down(ss, off_, 16);
    }
    s = __shfl(s, 0, 16); ss = __shfl(ss, 0, 16);
    const float mu = s * (1.f / 512.f);
    const float rinv = rsqrtf(fmaxf(ss * (1.f / 512.f) - mu * mu, 0.f) + 1e-5f);
#pragma unroll
    for (int j = 0; j < 32; ++j) {
        int c = i * 32 + j;
        float y = (val[j] - mu) * rinv * b2f(gamma[c]) + b2f(beta[c]);
        cur[r * 520 + c] = f2b(y);
    }
}

__global__ __launch_bounds__(256)
void tail_kernel(const unsigned short* __restrict__ S2,
                 const unsigned short* __restrict__ Wo2, const unsigned short* __restrict__ bo2,
                 const unsigned short* __restrict__ Wf2, const unsigned short* __restrict__ fb2,
                 const unsigned short* __restrict__ Wc,  const unsigned short* __restrict__ bc,
                 const unsigned short* __restrict__ Wf3, const unsigned short* __restrict__ fb3,
                 const unsigned short* __restrict__ g12, const unsigned short* __restrict__ b12,
                 const unsigned short* __restrict__ g22, const unsigned short* __restrict__ b22,
                 const unsigned short* __restrict__ g13, const unsigned short* __restrict__ b13,
                 const unsigned short* __restrict__ g23, const unsigned short* __restrict__ b23,
                 const unsigned short* __restrict__ seedv,
                 const int* __restrict__ lens, void* __restrict__ out,
                 const int* __restrict__ flag, size_t elem_off) {
    __shared__ unsigned short cur[16 * 520];
    __shared__ unsigned short tmp[16 * 520];
    const int t = threadIdx.x;
    const int rbase = blockIdx.x * 16;
    const int r = t >> 4, i = t & 15;

#pragma unroll
    for (int j = 0; j < 4; ++j)
        *(uint4*)&cur[r * 520 + i * 32 + j * 8] =
            *(const uint4*)&S2[(size_t)(rbase + r) * 512 + i * 32 + j * 8];
    __syncthreads();

    tail_matvec(cur, tmp, Wo2, bo2, 0, t); __syncthreads();
    tail_ln(cur, tmp, g12, b12, seedv, t); __syncthreads();
    tail_matvec(cur, tmp, Wf2, fb2, 1, t); __syncthreads();
    tail_ln(cur, tmp, g22, b22, nullptr, t); __syncthreads();
    tail_matvec(cur, tmp, Wc, bc, 0, t); __syncthreads();
    tail_ln(cur, tmp, g13, b13, nullptr, t); __syncthreads();
    tail_matvec(cur, tmp, Wf3, fb3, 1, t); __syncthreads();
    tail_ln(cur, tmp, g23, b23, nullptr, t); __syncthreads();

    const int rg = rbase + r;
    const bool ok = lens[rg] > 0;
    if (*flag) {
#pragma unroll
        for (int j = 0; j < 4; ++j) {
            uint4 v = make_uint4(0u, 0u, 0u, 0u);
            if (ok) v = *(uint4*)&cur[r * 520 + i * 32 + j * 8];
            *(uint4*)((unsigned short*)out + elem_off + (size_t)rg * 512 + i * 32 + j * 8) = v;
        }
    } else {
#pragma unroll
        for (int j = 0; j < 4; ++j) {
            float x[8] = {};
            if (ok) unpack8(*(uint4*)&cur[r * 520 + i * 32 + j * 8], x);
            float* o = (float*)out + elem_off + (size_t)rg * 512 + i * 32 + j * 8;
            *(float4*)o       = make_float4(x[0], x[1], x[2], x[3]);
            *(float4*)(o + 4) = make_float4(x[4], x[5], x[6], x[7]);
        }
    }
}

extern "C" void kernel_launch(void* const* d_in, const int* in_sizes, int n_in,
                              void* d_out, int out_size, void* d_ws, size_t ws_size,
                              hipStream_t stream) {
    (void)in_sizes; (void)n_in;
    const void* gene = d_in[0];
    const int*  gidx = (const int*)d_in[1];
    const int*  lens = (const int*)d_in[2];

    // ---- workspace header: flag, meta(2), off[4096] ints ----
    int* ibase = (int*)d_ws;
    int* flag  = ibase;
    int* meta  = ibase + 2;
    int* d_off = ibase + 8;
    unsigned short* ws0 = (unsigned short*)(ibase + 8 + 4096);
    const size_t hdr_bytes = (size_t)(8 + 4096) * 4;

    size_t off = 0;
    auto take = [&](size_t elems) { unsigned short* p = ws0 + off; off += elems; return p; };
    const size_t CC = (size_t)C_ * C_;
    unsigned short* wEnc0 = take(3 * CC);   // [Wq0;Wk0;Wv0]  (1536 x 512)
    unsigned short* wEnc1 = take(3 * CC);   // [Wq1;Wk1;Wv1]
    unsigned short* wKVp  = take(2 * CC);   // [Wk2;Wv2]      (1024 x 512)
    unsigned short* wO  = take(4 * CC);
    unsigned short* wF  = take(4 * CC);
    unsigned short* wP  = take(CC);
    unsigned short* wQp = take(CC);         // Wq2
    unsigned short* wVd = take(CC);         // Wv3
    unsigned short* wWc = take(CC);         // Wo3 @ Wv3 (decoder collapse)
    unsigned short* cbq = take(4 * C_);
    unsigned short* cbk = take(4 * C_);
    unsigned short* cbv = take(4 * C_);
    unsigned short* cbo = take(4 * C_);
    unsigned short* cff = take(4 * C_);
    unsigned short* cg1 = take(4 * C_);
    unsigned short* cb1 = take(4 * C_);
    unsigned short* cg2 = take(4 * C_);
    unsigned short* cb2 = take(4 * C_);
    unsigned short* cpb = take(C_);
    unsigned short* csd = take(C_);
    unsigned short* bqkv0 = take(3 * C_);
    unsigned short* bqkv1 = take(3 * C_);
    unsigned short* bkv2  = take(2 * C_);
    unsigned short* bcb   = take(C_);       // Wo3 bv3 + bo3
    unsigned short* qp    = take(C_);
    const size_t wbytes = hdr_bytes + off * 2;

    // per-reaction: X(32*512) + AQKV(32*1536) + Aout(32*512) + S2(512) elems
    const size_t per_r = ((size_t)32 * 2560 + 512) * 2;
    int Rc = 0;
    const int cands[6] = {4096, 2048, 1024, 512, 256, 128};
    for (int i = 0; i < 6; ++i) {
        size_t need = wbytes + (size_t)cands[i] * per_r;
        if (need <= ws_size) { Rc = cands[i]; break; }
    }
    if (Rc == 0) {
        diag_kernel<<<(out_size + 255) / 256, 256, 0, stream>>>(
            (unsigned short*)d_out, out_size, 1000.0f + (float)(ws_size >> 20));
        return;
    }
    const int Mc = Rc * 32;

    unsigned short* X    = take((size_t)Mc * C_);
    unsigned short* AQKV = take((size_t)Mc * 1536);
    unsigned short* Aout = take((size_t)Mc * C_);
    unsigned short* S2 = take((size_t)Rc * C_);

    detect_kernel<<<1, 256, 0, stream>>>((const unsigned short*)gene, flag);
    auto cvt = [&](const void* in, unsigned short* out_, int n, int src_off) {
        cvt_any_kernel<<<(n + 2047) / 2048, 256, 0, stream>>>(in, out_, n, flag, src_off);
    };
    // encoder QKV concats (blocks 0,1)
    cvt(d_in[3], wEnc0,          (int)CC, 0);
    cvt(d_in[4], wEnc0 + CC,     (int)CC, 0);
    cvt(d_in[5], wEnc0 + 2 * CC, (int)CC, 0);
    cvt(d_in[3], wEnc1,          (int)CC, (int)CC);
    cvt(d_in[4], wEnc1 + CC,     (int)CC, (int)CC);
    cvt(d_in[5], wEnc1 + 2 * CC, (int)CC, (int)CC);
    // PMA KV concat (block 2), PMA Wq, dec Wv (block 3)
    cvt(d_in[4], wKVp,      (int)CC, (int)(2 * CC));
    cvt(d_in[5], wKVp + CC, (int)CC, (int)(2 * CC));
    cvt(d_in[3], wQp, (int)CC, (int)(2 * CC));
    cvt(d_in[5], wVd, (int)CC, (int)(3 * CC));
    cvt(d_in[6], wO, (int)(4 * CC), 0);
    cvt(d_in[7], wF, (int)(4 * CC), 0);
    cvt(d_in[17], wP, (int)CC, 0);
    cvt(d_in[8],  cbq, 4 * C_, 0); cvt(d_in[9],  cbk, 4 * C_, 0); cvt(d_in[10], cbv, 4 * C_, 0);
    cvt(d_in[11], cbo, 4 * C_, 0); cvt(d_in[12], cff, 4 * C_, 0);
    cvt(d_in[13], cg1, 4 * C_, 0); cvt(d_in[14], cb1, 4 * C_, 0);
    cvt(d_in[15], cg2, 4 * C_, 0); cvt(d_in[16], cb2, 4 * C_, 0);
    cvt(d_in[18], cpb, C_, 0);     cvt(d_in[19], csd, C_, 0);
    bias_concat_kernel<<<1, 256, 0, stream>>>(cbq, cbk, cbv, bqkv0, bqkv1, bkv2);
    qp_kernel<<<1, 256, 0, stream>>>(wQp, cbq + 2 * C_, csd, qp);
    wc_kernel<<<512, 256, 0, stream>>>(wO + 3 * CC, wVd, wWc);
    bc_kernel<<<2, 256, 0, stream>>>(wO + 3 * CC, cbv + 3 * C_, cbo + 3 * C_, bcb);

    auto gemm = [&](auto nt_tag, const unsigned short* Ain, const unsigned short* Win,
                    const unsigned short* bias, unsigned short* Outp, int Mrows, int relu,
                    const int* mt) {
        constexpr int NT = decltype(nt_tag)::value;
        const int MT = Mrows / 128;
        const int grid = 8 * ((MT + 7) / 8) * NT;
        gemm_bt_kernel<NT><<<dim3(grid), 256, 0, stream>>>(Ain, Win, bias, Outp, relu, mt, MT);
    };
    using N2 = std::integral_constant<int, 2>;
    using N4 = std::integral_constant<int, 4>;
    using N6 = std::integral_constant<int, 6>;

    for (int c = 0; c < R_ / Rc; ++c) {
        const int r0 = c * Rc;
        const int* lc = lens + r0;

        scan_kernel<<<1, 256, 0, stream>>>(lc, d_off, meta, Rc);
        gather_kernel<<<Mc * 64 / 256, 256, 0, stream>>>(
            gene, gidx + (size_t)r0 * L_, lc, d_off, X, flag);
        ztail_kernel<<<32, 256, 0, stream>>>(X, meta);

        for (int i = 0; i < 2; ++i) {
            gemm(N6{}, X, i ? wEnc1 : wEnc0, i ? bqkv1 : bqkv0, AQKV, Mc, 0, meta);
            attn_enc_kernel<<<dim3(Rc, H_), 128, 0, stream>>>(AQKV, Aout, lc, d_off);
            gemm(N2{}, Aout, wO + (size_t)i * CC, cbo + i * C_, AQKV, Mc, 0, meta);  // reuse AQKV as tmp
            ln_kernel<<<Mc / 4, 256, 0, stream>>>(AQKV, X, cg1 + i * C_, cb1 + i * C_, X, lc, 0, meta);
            gemm(N2{}, X, wF + (size_t)i * CC, cff + i * C_, Aout, Mc, 1, meta);
            ln_kernel<<<Mc / 4, 256, 0, stream>>>(Aout, X, cg2 + i * C_, cb2 + i * C_, X, lc, 0, meta);
        }

        gemm(N2{}, X, wP, cpb, Aout, Mc, 1, meta);                // Y = relu(X Wp + bp)

        // PMA: KV via MFMA GEMM (proven), light attention kernel
        gemm(N4{}, Aout, wKVp, bkv2, AQKV, Mc, 0, meta);          // fused K|V (stride 1024)
        attn_pma_kernel<<<dim3(Rc, H_), 64, 0, stream>>>(qp, AQKV, S2, lc, d_off);

        // fused tail: Wo2+LN, FF2+LN, Wc+LN, FF3+LN, final write
        tail_kernel<<<Rc / 16, 256, 0, stream>>>(
            S2,
            wO + 2 * CC, cbo + 2 * C_,
            wF + 2 * CC, cff + 2 * C_,
            wWc, bcb,
            wF + 3 * CC, cff + 3 * C_,
            cg1 + 2 * C_, cb1 + 2 * C_, cg2 + 2 * C_, cb2 + 2 * C_,
            cg1 + 3 * C_, cb1 + 3 * C_, cg2 + 3 * C_, cb2 + 3 * C_,
            csd, lc, d_out, flag, (size_t)r0 * C_);
    }
}